// Round 7
// baseline (193.737 us; speedup 1.0000x reference)
//
#include <hip/hip_runtime.h>

// LocalizationLoss: B=1048576, N=3, C=7. output (B,3,7) fp32, target (B,3,5) fp32.
// result = (5*(Sx+Sy+2*Swh) + 3*Sce - 0.5*Sbce)/(B*N) + 0.5   (scalar fp32)
//
// History: R3 barrier-dbuf 62us. R5 TLP-20waves 58us. R6 gl_lds rotate ~55us.
// R7 misaligned CRASH. R8 reg-stage spills. R9 reg rotation collapsed 77us.
// R10 pinned spills 159us. R11 counted vmcnt(5)+asm ds_reads: ~52us PASS —
// killed the vmcnt-drain theory (plateau ~3 TB/s demand unchanged).
// R12 single-buffer + launch_bounds(256,8): absmax=inf (WAR on same-buffer
// refill and/or VGPR-64 cap vs ~54 live asm regs). TLP question unanswered.
// R13 = R11 skeleton (PASSED) with ONE axis changed: 16-row shots.
//  - 2 rotating buffers/wave: 2*(16*21+16*15)*4B = 4608 B/wave -> 18432/block
//    -> 8 blocks/CU = 32 waves/CU (HW max) by LDS. NO launch-bounds cap;
//    live set ~54 VGPR expected <=64 naturally.
//  - counted WAITV(3): one 3-gl_lds stage always in flight; refill goes to
//    the OTHER buffer (no WAR). 8 shots/wave.
//  - rows duplicate 4-way across lanes (r = lane&15, LDS broadcast is free);
//    finalize scales by 0.25.
// Discriminator: if 2x occupancy leaves ~50us/3TB/s -> read-path ceiling
// (vs 6.7 TB/s fill write reference) -> ROOFLINE.

#define NBLK 2048            // 2048 blk x 4 waves x 8 shots x 16 rows = B
#define INV_BN (1.0f / 3145728.0f)

typedef float v2f __attribute__((ext_vector_type(2)));

__device__ __forceinline__ void gl16(const float4* g, float4* l) {
  __builtin_amdgcn_global_load_lds(
      (const __attribute__((address_space(1))) unsigned int*)g,
      (__attribute__((address_space(3))) unsigned int*)l, 16, 0, 0);
}

// Stage 16 rows: o = 16*21 = 84 float4; t = 16*15 = 60 float4. 3 gl_lds/wave.
__device__ __forceinline__ void stage16(const float* __restrict__ gout,
                                        const float* __restrict__ gtgt,
                                        size_t row0, int lane,
                                        float* so, float* st) {
  const float4* go4 = (const float4*)(gout + row0 * 21);
  const float4* gt4 = (const float4*)(gtgt + row0 * 15);
  float4* so4 = (float4*)so;
  float4* st4 = (float4*)st;
  gl16(go4 + lane, so4);
  if (lane < 20) gl16(go4 + 64 + lane, so4 + 64);
  if (lane < 60) gl16(gt4 + lane, st4);
}

#define FENCE()                              \
  asm volatile("" ::: "memory");             \
  __builtin_amdgcn_sched_barrier(0)

#define WAITV(n)                                           \
  FENCE();                                                 \
  asm volatile("s_waitcnt vmcnt(" #n ")" ::: "memory");    \
  __builtin_amdgcn_sched_barrier(0)

#define DS2(dst, addr, a, b)                                          \
  asm volatile("ds_read2_b32 %0, %1 offset0:" #a " offset1:" #b       \
               : "=v"(dst) : "v"(addr))

// Opaque row read + math (verbatim from R11, which PASSED).
__device__ __forceinline__ float row_math(unsigned oa, unsigned ta) {
  v2f oP0, oP1, oP2, oP3, oP4, oP5, oP6, oP7, oP8, oP9;
  float of20;
  v2f tP0, tP1, tP2, tP3, tP4, tP5, tP6;
  float tf14;
  DS2(oP0, oa, 0, 1);   DS2(oP1, oa, 2, 3);   DS2(oP2, oa, 4, 5);
  DS2(oP3, oa, 6, 7);   DS2(oP4, oa, 8, 9);   DS2(oP5, oa, 10, 11);
  DS2(oP6, oa, 12, 13); DS2(oP7, oa, 14, 15); DS2(oP8, oa, 16, 17);
  DS2(oP9, oa, 18, 19);
  asm volatile("ds_read_b32 %0, %1 offset:80" : "=v"(of20) : "v"(oa));
  DS2(tP0, ta, 0, 1);   DS2(tP1, ta, 2, 3);   DS2(tP2, ta, 4, 5);
  DS2(tP3, ta, 6, 7);   DS2(tP4, ta, 8, 9);   DS2(tP5, ta, 10, 11);
  DS2(tP6, ta, 12, 13);
  asm volatile("ds_read_b32 %0, %1 offset:56" : "=v"(tf14) : "v"(ta));
  asm volatile("s_waitcnt lgkmcnt(0)" ::: "memory");
  __builtin_amdgcn_sched_barrier(0);   // rule #18: no VALU hoists past the wait

  float pbce = 1.f, sx = 0.f, sy = 0.f, swh = 0.f, sel = 0.f;
  float Lg[3][3];
  // n = 0
  {
    const bool mk = (tP0.x != 0.f);
    const float m = mk ? 1.f : 0.f;
    pbce *= mk ? oP0.x : 1.f - oP0.x;
    const float dx = oP0.y * m - tP0.y; sx += dx * dx;
    const float dy = oP1.x * m - tP1.x; sy += dy * dy;
    const float o3 = oP1.y, t3 = tP1.y;
    swh += t3 + (mk ? (o3 - 2.f * __builtin_sqrtf(o3 * t3)) : 0.f);
    Lg[0][0] = oP2.x * m; Lg[0][1] = oP2.y * m; Lg[0][2] = oP3.x * m;
  }
  // n = 1
  {
    const bool mk = (tP2.y != 0.f);
    const float m = mk ? 1.f : 0.f;
    pbce *= mk ? oP3.y : 1.f - oP3.y;
    const float dx = oP4.x * m - tP3.x; sx += dx * dx;
    const float dy = oP4.y * m - tP3.y; sy += dy * dy;
    const float o3 = oP5.x, t3 = tP4.x;
    swh += t3 + (mk ? (o3 - 2.f * __builtin_sqrtf(o3 * t3)) : 0.f);
    Lg[1][0] = oP5.y * m; Lg[1][1] = oP6.x * m; Lg[1][2] = oP6.y * m;
  }
  // n = 2
  {
    const bool mk = (tP5.x != 0.f);
    const float m = mk ? 1.f : 0.f;
    pbce *= mk ? oP7.x : 1.f - oP7.x;
    const float dx = oP7.y * m - tP5.y; sx += dx * dx;
    const float dy = oP8.x * m - tP6.x; sy += dy * dy;
    const float o3 = oP8.y, t3 = tP6.y;
    swh += t3 + (mk ? (o3 - 2.f * __builtin_sqrtf(o3 * t3)) : 0.f);
    Lg[2][0] = oP9.x * m; Lg[2][1] = oP9.y * m; Lg[2][2] = of20 * m;
  }
  const int cls[3] = {(int)tP2.x, (int)tP4.y, (int)tf14};
  float prodS = 1.f;
  #pragma unroll
  for (int j = 0; j < 3; ++j) {
    prodS *= __expf(Lg[0][j]) + __expf(Lg[1][j]) + __expf(Lg[2][j]);
    const int idx = cls[j];
    sel += (idx == 0) ? Lg[0][j] : ((idx == 1) ? Lg[1][j] : Lg[2][j]);
  }
  return 5.f * (sx + sy + 2.f * swh) + 3.f * (__logf(prodS) - sel)
         - 0.5f * __logf(pbce);
}

__global__ __launch_bounds__(256) void loc_loss_kernel(
    const float* __restrict__ gout, const float* __restrict__ gtgt,
    float* __restrict__ ws) {
  // 2 rotating wave-private 16-row buffers x 4 waves = 18432 B/block
  // -> 8 blocks/CU (LDS-limited) -> 32 waves/CU.
  __shared__ alignas(16) float sA_out[4][16 * 21];
  __shared__ alignas(16) float sA_tgt[4][16 * 15];
  __shared__ alignas(16) float sB_out[4][16 * 21];
  __shared__ alignas(16) float sB_tgt[4][16 * 15];

  const int tid = threadIdx.x;
  const int w = tid >> 6;
  const int lane = tid & 63;
  const int r = lane & 15;  // 4-way duplicated rows (broadcast LDS reads)
  const size_t base = ((size_t)blockIdx.x * 4 + w) * 128;  // 8 shots x 16 rows

  const unsigned oA = (unsigned)(uintptr_t)(
      (__attribute__((address_space(3))) float*)&sA_out[w][0]) + r * 84u;
  const unsigned tA = (unsigned)(uintptr_t)(
      (__attribute__((address_space(3))) float*)&sA_tgt[w][0]) + r * 60u;
  const unsigned oB = (unsigned)(uintptr_t)(
      (__attribute__((address_space(3))) float*)&sB_out[w][0]) + r * 60u * 0u
      + (unsigned)(uintptr_t)(
      (__attribute__((address_space(3))) float*)&sB_out[w][0]) * 0u
      + (unsigned)(uintptr_t)(
      (__attribute__((address_space(3))) float*)&sB_out[w][0]) + r * 84u
      - (unsigned)(uintptr_t)(
      (__attribute__((address_space(3))) float*)&sB_out[w][0]);
  const unsigned tB = (unsigned)(uintptr_t)(
      (__attribute__((address_space(3))) float*)&sB_tgt[w][0]) + r * 60u;

  float acc = 0.f;
  // s0->A, s1->B | shot k: WAITV(3) (drain stage k; k+1 in flight), read,
  // refill stage k+2 into the buffer just read, math. Shots 6/7: no refill.
  stage16(gout, gtgt, base +   0, lane, sA_out[w], sA_tgt[w]);
  stage16(gout, gtgt, base +  16, lane, sB_out[w], sB_tgt[w]);
  WAITV(3);
  { FENCE(); stage16(gout, gtgt, base +  32, lane, sA_out[w], sA_tgt[w]); }
  acc += row_math(oA, tA);
  WAITV(3);
  { FENCE(); stage16(gout, gtgt, base +  48, lane, sB_out[w], sB_tgt[w]); }
  acc += row_math(oB, tB);
  WAITV(3);
  { FENCE(); stage16(gout, gtgt, base +  64, lane, sA_out[w], sA_tgt[w]); }
  acc += row_math(oA, tA);
  WAITV(3);
  { FENCE(); stage16(gout, gtgt, base +  80, lane, sB_out[w], sB_tgt[w]); }
  acc += row_math(oB, tB);
  WAITV(3);
  { FENCE(); stage16(gout, gtgt, base +  96, lane, sA_out[w], sA_tgt[w]); }
  acc += row_math(oA, tA);
  WAITV(3);
  { FENCE(); stage16(gout, gtgt, base + 112, lane, sB_out[w], sB_tgt[w]); }
  acc += row_math(oB, tB);
  WAITV(3);
  acc += row_math(oA, tA);
  WAITV(0);
  acc += row_math(oB, tB);

  // 4-way duplicated rows -> wave sum = 4x row-sum; finalize scales 0.25.
  #pragma unroll
  for (int off = 32; off > 0; off >>= 1) acc += __shfl_down(acc, off, 64);
  if (lane == 0) ws[(size_t)blockIdx.x * 4 + w] = acc;
}

__global__ __launch_bounds__(256) void loc_loss_finalize(
    const float* __restrict__ ws, float* __restrict__ out) {
  __shared__ float s_wave[4];
  const int tid = threadIdx.x;
  const float4* w4 = (const float4*)ws;  // 8192 partials = 2048 float4
  float acc = 0.f;
  #pragma unroll
  for (int i = 0; i < 8; ++i) {
    float4 v = w4[tid + 256 * i];
    acc += (v.x + v.y) + (v.z + v.w);
  }
  #pragma unroll
  for (int off = 32; off > 0; off >>= 1) acc += __shfl_down(acc, off, 64);
  if ((tid & 63) == 0) s_wave[tid >> 6] = acc;
  __syncthreads();
  if (tid == 0) {
    // 0.25x undoes the 4-way duplicated-lane compute.
    out[0] = (s_wave[0] + s_wave[1] + s_wave[2] + s_wave[3])
             * (0.25f * INV_BN) + 0.5f;
  }
}

extern "C" void kernel_launch(void* const* d_in, const int* in_sizes, int n_in,
                              void* d_out, int out_size, void* d_ws, size_t ws_size,
                              hipStream_t stream) {
  const float* gout = (const float*)d_in[0];  // (B,3,7)
  const float* gtgt = (const float*)d_in[1];  // (B,3,5)
  float* ws = (float*)d_ws;                   // 8192 floats = 32 KB
  float* out = (float*)d_out;

  loc_loss_kernel<<<NBLK, 256, 0, stream>>>(gout, gtgt, ws);
  loc_loss_finalize<<<1, 256, 0, stream>>>(ws, out);
}

// Round 8
// 163.463 us; speedup vs baseline: 1.1852x; 1.1852x over previous
//
#include <hip/hip_runtime.h>

// LocalizationLoss: B=1048576, N=3, C=7. output (B,3,7) fp32, target (B,3,5) fp32.
// result = (5*(Sx+Sy+2*Swh) + 3*Sce - 0.5*Sbce)/(B*N) + 0.5   (scalar fp32)
//
// FINAL (R14 = R11 verbatim, best verified: 162.3us total, kernel ~52us).
//
// ROOFLINE POST-MORTEM (8 rounds):
//  Six independent structures -- R3 barrier-dbuf (62us), R5 TLP-only VGPR=28
//  20waves/CU (58us), R6 gl_lds 4-shot rotate+NT (~55us), R8 reg-staging incl.
//  spill traffic (2.5 TB/s), R11 counted-vmcnt asm with prefetch provably in
//  flight (~52us), R13 16-row asm (77us) -- ALL pin total demand traffic at
//  2.3-3.0 TB/s, invariant to ILP depth, TLP, staging path, waitcnt policy,
//  NT hints. Falsified hypotheses: vmcnt-drain (R11), misalignment (R7),
//  spills (R9 clean), TLP shortage (R5 20w = R11 12w).
//  Reference (rule #10): m13 float4 copy = 6.29 TB/s TOTAL traffic (79% of
//  8 TB/s bidirectional peak) => ~3.15 TB/s read-side; fills here do 6.7 TB/s
//  write-side. Our 2.9 TB/s pure-read = ~92% of the chip's reference
//  read-side rate on a half-L3-resident buffer set (FETCH 73.8 of 151 MB).
//  Reads are latency x per-CU-outstanding-capacity limited; no HIP-source
//  lever moved the product in 8 rounds.
//  Floor: 151 MB / ~3.1 TB/s ~= 49us kernel + ~108us harness (2x52us
//  re-poison fills + finalize + gaps) ~= 157us total. This kernel: 162.3us.
//
// Structure: 2 rotating wave-private LDS buffers x 4 waves; 4 shots x 32 rows;
// global_load_lds staging (aux=2 NT); asm-opaque ds_read2_b32 row reads so the
// compiler inserts no vmcnt for them; manual counted s_waitcnt vmcnt(5) keeps
// the newest stage in flight across each compute phase (vmcnt(0) only at the
// last); rule #18 lgkmcnt(0)+sched_barrier after read clusters; full-wave
// compute row=lane&31 (upper half duplicates, LDS broadcast free; finalize
// scales 0.5).

#define NBLK 2048            // 2048 blocks x 4 waves x 4 shots x 32 rows = B
#define INV_BN (1.0f / 3145728.0f)

typedef float v2f __attribute__((ext_vector_type(2)));

__device__ __forceinline__ void gl16(const float4* g, float4* l) {
  // aux=2 -> NT (evict-first)
  __builtin_amdgcn_global_load_lds(
      (const __attribute__((address_space(1))) unsigned int*)g,
      (__attribute__((address_space(3))) unsigned int*)l, 16, 0, 2);
}

// Stage 32 rows: o = 32*21 = 168 float4; t = 32*15 = 120 float4. 5 gl_lds
// issued per call regardless of lane masks (wave-level vmcnt += 5).
__device__ __forceinline__ void stage32(const float* __restrict__ gout,
                                        const float* __restrict__ gtgt,
                                        size_t row0, int lane,
                                        float* so, float* st) {
  const float4* go4 = (const float4*)(gout + row0 * 21);
  const float4* gt4 = (const float4*)(gtgt + row0 * 15);
  float4* so4 = (float4*)so;
  float4* st4 = (float4*)st;
  gl16(go4 + lane, so4);
  gl16(go4 + 64 + lane, so4 + 64);
  if (lane < 40) gl16(go4 + 128 + lane, so4 + 128);
  gl16(gt4 + lane, st4);
  if (lane < 56) gl16(gt4 + 64 + lane, st4 + 64);
}

#define FENCE()                              \
  asm volatile("" ::: "memory");             \
  __builtin_amdgcn_sched_barrier(0)

#define WAITV(n)                                           \
  FENCE();                                                 \
  asm volatile("s_waitcnt vmcnt(" #n ")" ::: "memory");    \
  __builtin_amdgcn_sched_barrier(0)

#define DS2(dst, addr, a, b)                                          \
  asm volatile("ds_read2_b32 %0, %1 offset0:" #a " offset1:" #b       \
               : "=v"(dst) : "v"(addr))

// Opaque row read + math. oa/ta = LDS byte addresses of this lane's row.
__device__ __forceinline__ float row_math(unsigned oa, unsigned ta) {
  v2f oP0, oP1, oP2, oP3, oP4, oP5, oP6, oP7, oP8, oP9;
  float of20;
  v2f tP0, tP1, tP2, tP3, tP4, tP5, tP6;
  float tf14;
  DS2(oP0, oa, 0, 1);   DS2(oP1, oa, 2, 3);   DS2(oP2, oa, 4, 5);
  DS2(oP3, oa, 6, 7);   DS2(oP4, oa, 8, 9);   DS2(oP5, oa, 10, 11);
  DS2(oP6, oa, 12, 13); DS2(oP7, oa, 14, 15); DS2(oP8, oa, 16, 17);
  DS2(oP9, oa, 18, 19);
  asm volatile("ds_read_b32 %0, %1 offset:80" : "=v"(of20) : "v"(oa));
  DS2(tP0, ta, 0, 1);   DS2(tP1, ta, 2, 3);   DS2(tP2, ta, 4, 5);
  DS2(tP3, ta, 6, 7);   DS2(tP4, ta, 8, 9);   DS2(tP5, ta, 10, 11);
  DS2(tP6, ta, 12, 13);
  asm volatile("ds_read_b32 %0, %1 offset:56" : "=v"(tf14) : "v"(ta));
  asm volatile("s_waitcnt lgkmcnt(0)" ::: "memory");
  __builtin_amdgcn_sched_barrier(0);   // rule #18: no VALU hoists past the wait

  float pbce = 1.f, sx = 0.f, sy = 0.f, swh = 0.f, sel = 0.f;
  float Lg[3][3];
  // n = 0
  {
    const bool mk = (tP0.x != 0.f);
    const float m = mk ? 1.f : 0.f;
    pbce *= mk ? oP0.x : 1.f - oP0.x;
    const float dx = oP0.y * m - tP0.y; sx += dx * dx;
    const float dy = oP1.x * m - tP1.x; sy += dy * dy;
    const float o3 = oP1.y, t3 = tP1.y;
    swh += t3 + (mk ? (o3 - 2.f * __builtin_sqrtf(o3 * t3)) : 0.f);
    Lg[0][0] = oP2.x * m; Lg[0][1] = oP2.y * m; Lg[0][2] = oP3.x * m;
  }
  // n = 1
  {
    const bool mk = (tP2.y != 0.f);
    const float m = mk ? 1.f : 0.f;
    pbce *= mk ? oP3.y : 1.f - oP3.y;
    const float dx = oP4.x * m - tP3.x; sx += dx * dx;
    const float dy = oP4.y * m - tP3.y; sy += dy * dy;
    const float o3 = oP5.x, t3 = tP4.x;
    swh += t3 + (mk ? (o3 - 2.f * __builtin_sqrtf(o3 * t3)) : 0.f);
    Lg[1][0] = oP5.y * m; Lg[1][1] = oP6.x * m; Lg[1][2] = oP6.y * m;
  }
  // n = 2
  {
    const bool mk = (tP5.x != 0.f);
    const float m = mk ? 1.f : 0.f;
    pbce *= mk ? oP7.x : 1.f - oP7.x;
    const float dx = oP7.y * m - tP5.y; sx += dx * dx;
    const float dy = oP8.x * m - tP6.x; sy += dy * dy;
    const float o3 = oP8.y, t3 = tP6.y;
    swh += t3 + (mk ? (o3 - 2.f * __builtin_sqrtf(o3 * t3)) : 0.f);
    Lg[2][0] = oP9.x * m; Lg[2][1] = oP9.y * m; Lg[2][2] = of20 * m;
  }
  const int cls[3] = {(int)tP2.x, (int)tP4.y, (int)tf14};
  float prodS = 1.f;
  #pragma unroll
  for (int j = 0; j < 3; ++j) {
    prodS *= __expf(Lg[0][j]) + __expf(Lg[1][j]) + __expf(Lg[2][j]);
    const int idx = cls[j];
    sel += (idx == 0) ? Lg[0][j] : ((idx == 1) ? Lg[1][j] : Lg[2][j]);
  }
  return 5.f * (sx + sy + 2.f * swh) + 3.f * (__logf(prodS) - sel)
         - 0.5f * __logf(pbce);
}

__global__ __launch_bounds__(256) void loc_loss_kernel(
    const float* __restrict__ gout, const float* __restrict__ gtgt,
    float* __restrict__ ws) {
  // 2 rotating wave-private buffers x 4 waves: 36864 B -> 4 blocks/CU.
  __shared__ alignas(16) float sA_out[4][32 * 21];
  __shared__ alignas(16) float sA_tgt[4][32 * 15];
  __shared__ alignas(16) float sB_out[4][32 * 21];
  __shared__ alignas(16) float sB_tgt[4][32 * 15];

  const int tid = threadIdx.x;
  const int w = tid >> 6;
  const int lane = tid & 63;
  const int r = lane & 31;  // duplicated rows on upper half-wave (broadcast)
  const size_t base = ((size_t)blockIdx.x * 4 + w) * 128;  // 4 shots x 32 rows

  // LDS byte addresses of this lane's row in each buffer (AS3 offset).
  const unsigned oA = (unsigned)(uintptr_t)(
      (__attribute__((address_space(3))) float*)&sA_out[w][0]) + r * 84u;
  const unsigned tA = (unsigned)(uintptr_t)(
      (__attribute__((address_space(3))) float*)&sA_tgt[w][0]) + r * 60u;
  const unsigned oB = (unsigned)(uintptr_t)(
      (__attribute__((address_space(3))) float*)&sB_out[w][0]) + r * 84u;
  const unsigned tB = (unsigned)(uintptr_t)(
      (__attribute__((address_space(3))) float*)&sB_tgt[w][0]) + r * 60u;

  float acc = 0.f;
  // Stages: s0->A, s1->B | wait(5): s0 done, s1 flying | read A, refill s2->A
  // | wait(5): s1 done, s2 flying | read B, refill s3->B | wait(5): s2 done
  // | read A | wait(0): s3 done | read B.
  stage32(gout, gtgt, base +  0, lane, sA_out[w], sA_tgt[w]);
  stage32(gout, gtgt, base + 32, lane, sB_out[w], sB_tgt[w]);
  WAITV(5);
  acc += row_math(oA, tA);
  FENCE();
  stage32(gout, gtgt, base + 64, lane, sA_out[w], sA_tgt[w]);
  WAITV(5);
  acc += row_math(oB, tB);
  FENCE();
  stage32(gout, gtgt, base + 96, lane, sB_out[w], sB_tgt[w]);
  WAITV(5);
  acc += row_math(oA, tA);
  WAITV(0);
  acc += row_math(oB, tB);

  // Lanes l and l+32 hold identical acc -> partial is 2x; finalize scales 0.5.
  #pragma unroll
  for (int off = 32; off > 0; off >>= 1) acc += __shfl_down(acc, off, 64);
  if (lane == 0) ws[(size_t)blockIdx.x * 4 + w] = acc;
}

__global__ __launch_bounds__(256) void loc_loss_finalize(
    const float* __restrict__ ws, float* __restrict__ out) {
  __shared__ float s_wave[4];
  const int tid = threadIdx.x;
  const float4* w4 = (const float4*)ws;  // 8192 partials = 2048 float4
  float acc = 0.f;
  #pragma unroll
  for (int i = 0; i < 8; ++i) {
    float4 v = w4[tid + 256 * i];
    acc += (v.x + v.y) + (v.z + v.w);
  }
  #pragma unroll
  for (int off = 32; off > 0; off >>= 1) acc += __shfl_down(acc, off, 64);
  if ((tid & 63) == 0) s_wave[tid >> 6] = acc;
  __syncthreads();
  if (tid == 0) {
    // 0.5x undoes duplicated-lane compute.
    out[0] = (s_wave[0] + s_wave[1] + s_wave[2] + s_wave[3])
             * (0.5f * INV_BN) + 0.5f;
  }
}

extern "C" void kernel_launch(void* const* d_in, const int* in_sizes, int n_in,
                              void* d_out, int out_size, void* d_ws, size_t ws_size,
                              hipStream_t stream) {
  const float* gout = (const float*)d_in[0];  // (B,3,7)
  const float* gtgt = (const float*)d_in[1];  // (B,3,5)
  float* ws = (float*)d_ws;                   // 8192 floats = 32 KB
  float* out = (float*)d_out;

  loc_loss_kernel<<<NBLK, 256, 0, stream>>>(gout, gtgt, ws);
  loc_loss_finalize<<<1, 256, 0, stream>>>(ws, out);
}